// Round 1
// baseline (1014.895 us; speedup 1.0000x reference)
//
#include <hip/hip_runtime.h>

using u64 = unsigned long long;

// ======================= Hilbert encode (Skilling) =======================
__device__ __forceinline__ int hilbert3(int X0, int X1, int X2) {
  #pragma unroll
  for (int Q = 256; Q > 1; Q >>= 1) {
    const int P = Q - 1;
    if (X0 & Q) X0 ^= P;
    int t1 = (X0 ^ X1) & P;
    if (X1 & Q) X0 ^= P; else { X0 ^= t1; X1 ^= t1; }
    int t2 = (X0 ^ X2) & P;
    if (X2 & Q) X0 ^= P; else { X0 ^= t2; X2 ^= t2; }
  }
  X1 ^= X0;
  X2 ^= X1;
  int t = 0;
  #pragma unroll
  for (int Q = 256; Q > 1; Q >>= 1) if (X2 & Q) t ^= (Q - 1);
  X0 ^= t; X1 ^= t; X2 ^= t;
  int code = 0;
  #pragma unroll
  for (int b = 8; b >= 0; b--)
    code = (code << 3) | (((X0 >> b) & 1) << 2) | (((X1 >> b) & 1) << 1) | ((X2 >> b) & 1);
  return code;
}

__global__ void encode_keys(const int* __restrict__ vox, u64* __restrict__ k1,
                            u64* __restrict__ k2, int n) {
  int i = blockIdx.x * blockDim.x + threadIdx.x;
  if (i >= n) return;
  int4 c = ((const int4*)vox)[i];              // (batch, z, y, x)
  unsigned code1 = (unsigned)hilbert3(c.y, c.z, c.w);   // (z,y,x)
  unsigned code2 = (unsigned)hilbert3(c.w, c.z, c.y);   // (x,y,z)
  u64 bb = ((u64)(unsigned)c.x << 45);
  k1[i] = bb | ((u64)code1 << 18) | (unsigned)i;
  k2[i] = bb | ((u64)code2 << 18) | (unsigned)i;
}

// ======================= Bitonic sort (N = 2^18, unique keys) ============
__global__ __launch_bounds__(1024) void bitonic_tile_sort(u64* __restrict__ keys) {
  __shared__ u64 s[2048];
  const int base = blockIdx.x * 2048;
  s[threadIdx.x]        = keys[base + threadIdx.x];
  s[threadIdx.x + 1024] = keys[base + threadIdx.x + 1024];
  __syncthreads();
  for (int k = 2; k <= 2048; k <<= 1) {
    for (int j = k >> 1; j >= 1; j >>= 1) {
      const int t = threadIdx.x;
      const int i = ((t & ~(j - 1)) << 1) | (t & (j - 1));
      const int l = i | j;
      const bool up = (((base + i) & k) == 0);
      u64 a = s[i], b = s[l];
      if ((a > b) == up) { s[i] = b; s[l] = a; }
      __syncthreads();
    }
  }
  keys[base + threadIdx.x]        = s[threadIdx.x];
  keys[base + threadIdx.x + 1024] = s[threadIdx.x + 1024];
}

__global__ void bitonic_gstep(u64* __restrict__ keys, int j, int k) {
  const int t = blockIdx.x * blockDim.x + threadIdx.x;
  const int i = ((t & ~(j - 1)) << 1) | (t & (j - 1));
  const int l = i | j;
  const bool up = ((i & k) == 0);
  u64 a = keys[i], b = keys[l];
  if ((a > b) == up) { keys[i] = b; keys[l] = a; }
}

__global__ __launch_bounds__(1024) void bitonic_tile_merge(u64* __restrict__ keys, int k) {
  __shared__ u64 s[2048];
  const int base = blockIdx.x * 2048;
  s[threadIdx.x]        = keys[base + threadIdx.x];
  s[threadIdx.x + 1024] = keys[base + threadIdx.x + 1024];
  __syncthreads();
  const bool up = ((base & k) == 0);  // k >= 4096 > tile => uniform per tile
  for (int j = 1024; j >= 1; j >>= 1) {
    const int t = threadIdx.x;
    const int i = ((t & ~(j - 1)) << 1) | (t & (j - 1));
    const int l = i | j;
    u64 a = s[i], b = s[l];
    if ((a > b) == up) { s[i] = b; s[l] = a; }
    __syncthreads();
  }
  keys[base + threadIdx.x]        = s[threadIdx.x];
  keys[base + threadIdx.x + 1024] = s[threadIdx.x + 1024];
}

__global__ void extract_inv_k(const u64* __restrict__ keys, int* __restrict__ ind,
                              int* __restrict__ inv, int n) {
  int t = blockIdx.x * blockDim.x + threadIdx.x;
  if (t >= n) return;
  int s = (int)(keys[t] & 0x3FFFFULL);
  ind[t] = s;
  inv[s] = t;
}

__global__ void make_g2_k(const u64* __restrict__ keys, const int* __restrict__ inv1,
                          int* __restrict__ ind2, int* __restrict__ g2, int n) {
  int t = blockIdx.x * blockDim.x + threadIdx.x;
  if (t >= n) return;
  int s = (int)(keys[t] & 0x3FFFFULL);
  ind2[t] = s;
  g2[t] = inv1[s];
}

// ======================= weight folding =======================
// M1 = Wq @ Wk^T  (scores = h M1 h^T / sqrt(C));  M2 = Wv @ Wo  (o2 = (attn h) M2)
__global__ void prep_M_k(const float* __restrict__ Wq, const float* __restrict__ Wk,
                         const float* __restrict__ Wv, const float* __restrict__ Wo,
                         float* __restrict__ M1, float* __restrict__ M2, int C) {
  int idx = blockIdx.x * blockDim.x + threadIdx.x;
  if (idx >= C * C) return;
  int a = idx / C, b = idx % C;
  float s1 = 0.f, s2 = 0.f;
  for (int c = 0; c < C; c++) {
    s1 = fmaf(Wq[a * C + c], Wk[b * C + c], s1);
    s2 = fmaf(Wv[a * C + c], Wo[c * C + b], s2);
  }
  M1[idx] = s1;
  M2[idx] = s2;
}

// ======================= attention block =======================
// Transposed LDS buffers [rows][64] with 16B-granule XOR swizzle to kill the
// 16-way bank conflict on the column-wise reads in t2 = attn @ h.
__device__ __forceinline__ int swzg(int row, int g) {
  return (row << 6) + ((((g) ^ (row >> 2)) & 15) << 2);
}
__device__ __forceinline__ int swz(int row, int col) {
  return swzg(row, col >> 2) + (col & 3);
}

template<int K, int WC>
__device__ __forceinline__ void mm_glob(const float* __restrict__ A, const float* __restrict__ B,
                                        const int ldB, const int rb, const int cb,
                                        float (&acc)[4][8]) {
  const int c0 = cb * WC;
  #pragma unroll 4
  for (int d = 0; d < K; d++) {
    const float4 av = *(const float4*)(A + swzg(d, rb));
    const float a[4] = {av.x, av.y, av.z, av.w};
    float bb[WC];
    #pragma unroll
    for (int jq = 0; jq < WC / 4; jq++) {
      const float4 bv = *(const float4*)(B + d * ldB + c0 + jq * 4);
      bb[jq * 4 + 0] = bv.x; bb[jq * 4 + 1] = bv.y;
      bb[jq * 4 + 2] = bv.z; bb[jq * 4 + 3] = bv.w;
    }
    #pragma unroll
    for (int i = 0; i < 4; i++)
      #pragma unroll
      for (int j = 0; j < WC; j++)
        acc[i][j] = fmaf(a[i], bb[j], acc[i][j]);
  }
}

template<int K>
__device__ __forceinline__ void mm_lds(const float* __restrict__ A, const float* __restrict__ B,
                                       const int rb, const int cb, float (&acc)[4][8]) {
  #pragma unroll 4
  for (int d = 0; d < K; d++) {
    const float4 av = *(const float4*)(A + swzg(d, rb));
    const float4 bv = *(const float4*)(B + swzg(d, cb));
    const float a[4] = {av.x, av.y, av.z, av.w};
    const float b[4] = {bv.x, bv.y, bv.z, bv.w};
    #pragma unroll
    for (int i = 0; i < 4; i++)
      #pragma unroll
      for (int j = 0; j < 4; j++)
        acc[i][j] = fmaf(a[i], b[j], acc[i][j]);
  }
}

template<int WC, bool RELU>
__device__ __forceinline__ void store_t(float* __restrict__ dst, const int rb, const int cb,
                                        const float (&acc)[4][8], const float scale) {
  const int c0 = cb * WC;
  #pragma unroll
  for (int j = 0; j < WC; j++) {
    float4 w;
    w.x = acc[0][j] * scale; w.y = acc[1][j] * scale;
    w.z = acc[2][j] * scale; w.w = acc[3][j] * scale;
    if (RELU) {
      w.x = fmaxf(w.x, 0.f); w.y = fmaxf(w.y, 0.f);
      w.z = fmaxf(w.z, 0.f); w.w = fmaxf(w.w, 0.f);
    }
    *(float4*)(dst + swzg(c0 + j, rb)) = w;
  }
}

template<int C>
__global__ __launch_bounds__(256) void block_k(
    const int* __restrict__ idx_p, const int* __restrict__ idx_x,
    const float* __restrict__ pts, const float* __restrict__ xsrc,
    const float* __restrict__ Wpos, const float* __restrict__ bpos,
    const float* __restrict__ M1, const float* __restrict__ M2,
    const float* __restrict__ Wout, float* __restrict__ outp, const float inv_scale) {
  constexpr int WC = C / 16;
  extern __shared__ float smem[];
  float* s_ht = smem;               // [C][64] swizzled: h^T (later relu(o2)^T)
  float* s_t1 = smem + C * 64;      // [C][64] swizzled: t1^T / t2^T (+ setup scratch)
  float* s_sc = smem + 2 * C * 64;  // [64][64] swizzled: scores^T / attn^T

  int*   s_src = (int*)s_t1;        // [64]   (dead before m1 writes t1)
  int*   s_sx  = (int*)s_t1 + 64;   // [64]
  float* s_p   = s_t1 + 128;        // [192]
  float* s_mn  = s_t1 + 320;        // [3]
  float* s_red = s_t1;              // [256]  (reused after m3, dead before m4 store)

  const int g  = blockIdx.x;
  const int t  = threadIdx.x;
  const int r  = t & 63;
  const int cq = t >> 6;
  const int rb = t >> 4;
  const int cb = t & 15;

  if (t < 64) {
    const int sp = idx_p[g * 64 + t];
    const int sx = idx_x[g * 64 + t];
    s_src[t] = sp;
    s_sx[t]  = sx;
    float px = pts[sp * 3 + 0], py = pts[sp * 3 + 1], pz = pts[sp * 3 + 2];
    s_p[t * 3 + 0] = px; s_p[t * 3 + 1] = py; s_p[t * 3 + 2] = pz;
    #pragma unroll
    for (int o = 32; o > 0; o >>= 1) {
      px += __shfl_xor(px, o);
      py += __shfl_xor(py, o);
      pz += __shfl_xor(pz, o);
    }
    if (t == 0) {
      s_mn[0] = px * (1.f / 64.f);
      s_mn[1] = py * (1.f / 64.f);
      s_mn[2] = pz * (1.f / 64.f);
    }
  }
  __syncthreads();

  // h = x * ((p - mean) @ Wpos + bpos), stored as h^T (swizzled)
  {
    const float d0 = s_p[r * 3 + 0] - s_mn[0];
    const float d1 = s_p[r * 3 + 1] - s_mn[1];
    const float d2 = s_p[r * 3 + 2] - s_mn[2];
    const float* xr = xsrc + (size_t)s_sx[r] * C;
    #pragma unroll
    for (int q4 = 0; q4 < C / 16; q4++) {
      const int c0 = cq * (C / 4) + q4 * 4;
      const float4 xv = *(const float4*)(xr + c0);
      const float e0 = fmaf(d0, Wpos[0 * C + c0 + 0], fmaf(d1, Wpos[1 * C + c0 + 0], fmaf(d2, Wpos[2 * C + c0 + 0], bpos[c0 + 0])));
      const float e1 = fmaf(d0, Wpos[0 * C + c0 + 1], fmaf(d1, Wpos[1 * C + c0 + 1], fmaf(d2, Wpos[2 * C + c0 + 1], bpos[c0 + 1])));
      const float e2 = fmaf(d0, Wpos[0 * C + c0 + 2], fmaf(d1, Wpos[1 * C + c0 + 2], fmaf(d2, Wpos[2 * C + c0 + 2], bpos[c0 + 2])));
      const float e3 = fmaf(d0, Wpos[0 * C + c0 + 3], fmaf(d1, Wpos[1 * C + c0 + 3], fmaf(d2, Wpos[2 * C + c0 + 3], bpos[c0 + 3])));
      s_ht[swz(c0 + 0, r)] = xv.x * e0;
      s_ht[swz(c0 + 1, r)] = xv.y * e1;
      s_ht[swz(c0 + 2, r)] = xv.z * e2;
      s_ht[swz(c0 + 3, r)] = xv.w * e3;
    }
  }
  __syncthreads();

  // m1: t1 = h @ M1
  {
    float acc[4][8] = {};
    mm_glob<C, WC>(s_ht, M1, C, rb, cb, acc);
    store_t<WC, false>(s_t1, rb, cb, acc, 1.f);
  }
  __syncthreads();

  // m3: sc = (t1 @ h^T) * inv_scale
  {
    float acc[4][8] = {};
    mm_lds<C>(s_t1, s_ht, rb, cb, acc);
    store_t<4, false>(s_sc, rb, cb, acc, inv_scale);
  }
  __syncthreads();

  // softmax over score axis j (sc stored as sc^T[j][r])
  {
    float ml = -3.0e38f;
    #pragma unroll
    for (int jj = 0; jj < 16; jj++) ml = fmaxf(ml, s_sc[swz(cq * 16 + jj, r)]);
    s_red[cq * 64 + r] = ml;
    __syncthreads();
    const float m = fmaxf(fmaxf(s_red[r], s_red[64 + r]), fmaxf(s_red[128 + r], s_red[192 + r]));
    __syncthreads();
    float sl = 0.f;
    #pragma unroll
    for (int jj = 0; jj < 16; jj++) {
      const int w = swz(cq * 16 + jj, r);
      const float v = __expf(s_sc[w] - m);
      s_sc[w] = v;
      sl += v;
    }
    s_red[cq * 64 + r] = sl;
    __syncthreads();
    const float inv = 1.f / (s_red[r] + s_red[64 + r] + s_red[128 + r] + s_red[192 + r]);
    #pragma unroll
    for (int jj = 0; jj < 16; jj++) s_sc[swz(cq * 16 + jj, r)] *= inv;
  }
  __syncthreads();

  // m4: t2 = attn @ h   (K = 64, reduction over group rows)
  {
    float acc[4][8] = {};
    const int c0 = cb * WC;
    #pragma unroll 2
    for (int jc = 0; jc < 16; jc++) {
      float4 av[4];
      #pragma unroll
      for (int jj = 0; jj < 4; jj++) av[jj] = *(const float4*)(s_sc + swzg(jc * 4 + jj, rb));
      #pragma unroll
      for (int jb = 0; jb < WC; jb++) {
        const float4 bv = *(const float4*)(s_ht + swzg(c0 + jb, jc));
        acc[0][jb] = fmaf(av[0].x, bv.x, fmaf(av[1].x, bv.y, fmaf(av[2].x, bv.z, fmaf(av[3].x, bv.w, acc[0][jb]))));
        acc[1][jb] = fmaf(av[0].y, bv.x, fmaf(av[1].y, bv.y, fmaf(av[2].y, bv.z, fmaf(av[3].y, bv.w, acc[1][jb]))));
        acc[2][jb] = fmaf(av[0].z, bv.x, fmaf(av[1].z, bv.y, fmaf(av[2].z, bv.z, fmaf(av[3].z, bv.w, acc[2][jb]))));
        acc[3][jb] = fmaf(av[0].w, bv.x, fmaf(av[1].w, bv.y, fmaf(av[2].w, bv.z, fmaf(av[3].w, bv.w, acc[3][jb]))));
      }
    }
    store_t<WC, false>(s_t1, rb, cb, acc, 1.f);
  }
  __syncthreads();

  // m5: o2r = relu(t2 @ M2) -> s_ht
  {
    float acc[4][8] = {};
    mm_glob<C, WC>(s_t1, M2, C, rb, cb, acc);
    store_t<WC, true>(s_ht, rb, cb, acc, 1.f);
  }
  __syncthreads();

  // m6: y = o2r @ Wout (64 x 128) -> global
  {
    float acc[4][8] = {};
    mm_glob<C, 8>(s_ht, Wout, 128, rb, cb, acc);
    const size_t base = ((size_t)g * 64 + rb * 4) * 128 + cb * 8;
    #pragma unroll
    for (int i = 0; i < 4; i++) {
      *(float4*)(outp + base + (size_t)i * 128 + 0) = make_float4(acc[i][0], acc[i][1], acc[i][2], acc[i][3]);
      *(float4*)(outp + base + (size_t)i * 128 + 4) = make_float4(acc[i][4], acc[i][5], acc[i][6], acc[i][7]);
    }
  }
}

// ======================= finalize =======================
__global__ void finalize_k(const int* __restrict__ ind2, const float* __restrict__ pts,
                           const int* __restrict__ vox, const int* __restrict__ numbs,
                           float* __restrict__ out_pts, float* __restrict__ out_vox,
                           float* __restrict__ out_nb, int n, int B) {
  int t = blockIdx.x * blockDim.x + threadIdx.x;
  if (t < n) {
    const int s = ind2[t];
    out_pts[t * 3 + 0] = pts[s * 3 + 0];
    out_pts[t * 3 + 1] = pts[s * 3 + 1];
    out_pts[t * 3 + 2] = pts[s * 3 + 2];
    const int4 v = ((const int4*)vox)[s];
    out_vox[t * 4 + 0] = (float)v.x;
    out_vox[t * 4 + 1] = (float)v.y;
    out_vox[t * 4 + 2] = (float)v.z;
    out_vox[t * 4 + 3] = (float)v.w;
  }
  if (t < B) out_nb[t] = (float)numbs[t];
}

// ======================= host =======================
extern "C" void kernel_launch(void* const* d_in, const int* in_sizes, int n_in,
                              void* d_out, int out_size, void* d_ws, size_t ws_size,
                              hipStream_t stream) {
  const int*   vox_numbs = (const int*)d_in[0];
  const int*   vox_coors = (const int*)d_in[1];
  const float* vox_feats = (const float*)d_in[2];
  const float* pts_coors = (const float*)d_in[3];
  const float* Wpos1 = (const float*)d_in[4];
  const float* bpos1 = (const float*)d_in[5];
  const float* Wq1   = (const float*)d_in[6];
  const float* Wk1   = (const float*)d_in[7];
  const float* Wv1   = (const float*)d_in[8];
  const float* Wo1   = (const float*)d_in[9];
  const float* Wout1 = (const float*)d_in[10];
  const float* Wpos2 = (const float*)d_in[11];
  const float* bpos2 = (const float*)d_in[12];
  const float* Wq2   = (const float*)d_in[13];
  const float* Wk2   = (const float*)d_in[14];
  const float* Wv2   = (const float*)d_in[15];
  const float* Wo2   = (const float*)d_in[16];
  const float* Wout2 = (const float*)d_in[17];

  const int B = in_sizes[0];
  const int n = in_sizes[1] / 4;       // 262144 = 2^18
  const int ngrp = n / 64;

  char* w = (char*)d_ws;
  auto alloc = [&](size_t bytes) {
    char* p = w;
    w += (bytes + 255) & ~(size_t)255;
    return p;
  };
  u64* keys1   = (u64*)alloc((size_t)n * 8);
  u64* keys2   = (u64*)alloc((size_t)n * 8);
  int* ind1    = (int*)alloc((size_t)n * 4);
  int* ind2    = (int*)alloc((size_t)n * 4);
  int* inv1    = (int*)alloc((size_t)n * 4);
  int* g2      = (int*)alloc((size_t)n * 4);
  float* M1a   = (float*)alloc(64 * 64 * 4);
  float* M2a   = (float*)alloc(64 * 64 * 4);
  float* M1b   = (float*)alloc(128 * 128 * 4);
  float* M2b   = (float*)alloc(128 * 128 * 4);
  float* feats1 = (float*)alloc((size_t)n * 128 * 4);

  float* out_feats = (float*)d_out;
  float* out_pts   = out_feats + (size_t)n * 128;
  float* out_vox   = out_pts + (size_t)n * 3;
  float* out_nb    = out_vox + (size_t)n * 4;

  auto f64  = block_k<64>;
  auto f128 = block_k<128>;
  hipFuncSetAttribute((const void*)f64,  hipFuncAttributeMaxDynamicSharedMemorySize, 49152);
  hipFuncSetAttribute((const void*)f128, hipFuncAttributeMaxDynamicSharedMemorySize, 81920);

  encode_keys<<<(n + 255) / 256, 256, 0, stream>>>(vox_coors, keys1, keys2, n);
  prep_M_k<<<(64 * 64 + 255) / 256, 256, 0, stream>>>(Wq1, Wk1, Wv1, Wo1, M1a, M2a, 64);
  prep_M_k<<<(128 * 128 + 255) / 256, 256, 0, stream>>>(Wq2, Wk2, Wv2, Wo2, M1b, M2b, 128);

  auto run_sort = [&](u64* keys) {
    bitonic_tile_sort<<<n / 2048, 1024, 0, stream>>>(keys);
    for (int k = 4096; k <= n; k <<= 1) {
      for (int j = k >> 1; j >= 2048; j >>= 1)
        bitonic_gstep<<<n / 512, 256, 0, stream>>>(keys, j, k);
      bitonic_tile_merge<<<n / 2048, 1024, 0, stream>>>(keys, k);
    }
  };
  run_sort(keys1);
  extract_inv_k<<<(n + 255) / 256, 256, 0, stream>>>(keys1, ind1, inv1, n);
  run_sort(keys2);
  make_g2_k<<<(n + 255) / 256, 256, 0, stream>>>(keys2, inv1, ind2, g2, n);

  block_k<64><<<ngrp, 256, 49152, stream>>>(ind1, ind1, pts_coors, vox_feats,
                                            Wpos1, bpos1, M1a, M2a, Wout1, feats1,
                                            0.125f);
  block_k<128><<<ngrp, 256, 81920, stream>>>(ind2, g2, pts_coors, feats1,
                                             Wpos2, bpos2, M1b, M2b, Wout2, out_feats,
                                             0.08838834764831845f);

  finalize_k<<<(n + 255) / 256, 256, 0, stream>>>(ind2, pts_coors, vox_coors, vox_numbs,
                                                  out_pts, out_vox, out_nb, n, B);
}

// Round 2
// 321.665 us; speedup vs baseline: 3.1551x; 3.1551x over previous
//
#include <hip/hip_runtime.h>

using u64 = unsigned long long;
typedef _Float16 f16;
using f16x8 = __attribute__((ext_vector_type(8))) _Float16;
using f16x4 = __attribute__((ext_vector_type(4))) _Float16;
using f32x4 = __attribute__((ext_vector_type(4))) float;

// ======================= Hilbert encode (Skilling) =======================
__device__ __forceinline__ int hilbert3(int X0, int X1, int X2) {
  #pragma unroll
  for (int Q = 256; Q > 1; Q >>= 1) {
    const int P = Q - 1;
    if (X0 & Q) X0 ^= P;
    int t1 = (X0 ^ X1) & P;
    if (X1 & Q) X0 ^= P; else { X0 ^= t1; X1 ^= t1; }
    int t2 = (X0 ^ X2) & P;
    if (X2 & Q) X0 ^= P; else { X0 ^= t2; X2 ^= t2; }
  }
  X1 ^= X0;
  X2 ^= X1;
  int t = 0;
  #pragma unroll
  for (int Q = 256; Q > 1; Q >>= 1) if (X2 & Q) t ^= (Q - 1);
  X0 ^= t; X1 ^= t; X2 ^= t;
  int code = 0;
  #pragma unroll
  for (int b = 8; b >= 0; b--)
    code = (code << 3) | (((X0 >> b) & 1) << 2) | (((X1 >> b) & 1) << 1) | ((X2 >> b) & 1);
  return code;
}

__global__ void encode_keys(const int* __restrict__ vox, u64* __restrict__ k1,
                            u64* __restrict__ k2, int n) {
  int i = blockIdx.x * blockDim.x + threadIdx.x;
  if (i >= n) return;
  int4 c = ((const int4*)vox)[i];              // (batch, z, y, x)
  unsigned code1 = (unsigned)hilbert3(c.y, c.z, c.w);   // (z,y,x)
  unsigned code2 = (unsigned)hilbert3(c.w, c.z, c.y);   // (x,y,z)
  u64 bb = ((u64)(unsigned)c.x << 45);
  k1[i] = bb | ((u64)code1 << 18) | (unsigned)i;
  k2[i] = bb | ((u64)code2 << 18) | (unsigned)i;
}

// ======================= Bitonic sort (2 arrays of n=2^18 via blockIdx.y) ==
__device__ __forceinline__ void cswap(u64& a, u64& b, bool up) {
  if ((a > b) == up) { u64 t = a; a = b; b = t; }
}

__global__ __launch_bounds__(1024) void bitonic_tile_sort(u64* __restrict__ keys, int n) {
  keys += (size_t)blockIdx.y * n;
  __shared__ u64 s[2048];
  const int base = blockIdx.x * 2048;
  s[threadIdx.x]        = keys[base + threadIdx.x];
  s[threadIdx.x + 1024] = keys[base + threadIdx.x + 1024];
  __syncthreads();
  for (int k = 2; k <= 2048; k <<= 1) {
    for (int j = k >> 1; j >= 1; j >>= 1) {
      const int t = threadIdx.x;
      const int i = ((t & ~(j - 1)) << 1) | (t & (j - 1));
      const int l = i | j;
      const bool up = (((base + i) & k) == 0);
      u64 a = s[i], b = s[l];
      if ((a > b) == up) { s[i] = b; s[l] = a; }
      __syncthreads();
    }
  }
  keys[base + threadIdx.x]        = s[threadIdx.x];
  keys[base + threadIdx.x + 1024] = s[threadIdx.x + 1024];
}

__global__ void bitonic_g1(u64* __restrict__ keys, int j, int k, int n) {
  keys += (size_t)blockIdx.y * n;
  const int t = blockIdx.x * blockDim.x + threadIdx.x;
  const int i = ((t & ~(j - 1)) << 1) | (t & (j - 1));
  const int l = i | j;
  const bool up = ((i & k) == 0);
  u64 a = keys[i], b = keys[l];
  if ((a > b) == up) { keys[i] = b; keys[l] = a; }
}

__global__ void bitonic_g2(u64* __restrict__ keys, int j2, int k, int n) {
  keys += (size_t)blockIdx.y * n;
  const int t = blockIdx.x * blockDim.x + threadIdx.x;
  const int i = ((t & ~(j2 - 1)) << 2) | (t & (j2 - 1));
  const bool up = ((i & k) == 0);
  u64 x0 = keys[i], x1 = keys[i + j2], x2 = keys[i + 2 * j2], x3 = keys[i + 3 * j2];
  cswap(x0, x2, up); cswap(x1, x3, up);   // level 2*j2
  cswap(x0, x1, up); cswap(x2, x3, up);   // level j2
  keys[i] = x0; keys[i + j2] = x1; keys[i + 2 * j2] = x2; keys[i + 3 * j2] = x3;
}

__global__ void bitonic_g3(u64* __restrict__ keys, int j4, int k, int n) {
  keys += (size_t)blockIdx.y * n;
  const int t = blockIdx.x * blockDim.x + threadIdx.x;
  const int i = ((t & ~(j4 - 1)) << 3) | (t & (j4 - 1));
  const bool up = ((i & k) == 0);
  u64 x[8];
  #pragma unroll
  for (int m = 0; m < 8; m++) x[m] = keys[i + m * j4];
  #pragma unroll
  for (int m = 0; m < 4; m++) cswap(x[m], x[m + 4], up);          // 4*j4
  cswap(x[0], x[2], up); cswap(x[1], x[3], up);
  cswap(x[4], x[6], up); cswap(x[5], x[7], up);                    // 2*j4
  #pragma unroll
  for (int m = 0; m < 8; m += 2) cswap(x[m], x[m + 1], up);        // j4
  #pragma unroll
  for (int m = 0; m < 8; m++) keys[i + m * j4] = x[m];
}

__global__ __launch_bounds__(1024) void bitonic_tile_merge(u64* __restrict__ keys, int k, int n) {
  keys += (size_t)blockIdx.y * n;
  __shared__ u64 s[2048];
  const int base = blockIdx.x * 2048;
  s[threadIdx.x]        = keys[base + threadIdx.x];
  s[threadIdx.x + 1024] = keys[base + threadIdx.x + 1024];
  __syncthreads();
  const bool up = ((base & k) == 0);  // k >= 4096 > tile => uniform per tile
  for (int j = 1024; j >= 1; j >>= 1) {
    const int t = threadIdx.x;
    const int i = ((t & ~(j - 1)) << 1) | (t & (j - 1));
    const int l = i | j;
    u64 a = s[i], b = s[l];
    if ((a > b) == up) { s[i] = b; s[l] = a; }
    __syncthreads();
  }
  keys[base + threadIdx.x]        = s[threadIdx.x];
  keys[base + threadIdx.x + 1024] = s[threadIdx.x + 1024];
}

__global__ void extract_inv_k(const u64* __restrict__ keys, int* __restrict__ ind,
                              int* __restrict__ inv, int n) {
  int t = blockIdx.x * blockDim.x + threadIdx.x;
  if (t >= n) return;
  int s = (int)(keys[t] & 0x3FFFFULL);
  ind[t] = s;
  inv[s] = t;
}

__global__ void make_g2_k(const u64* __restrict__ keys, const int* __restrict__ inv1,
                          int* __restrict__ ind2, int* __restrict__ g2, int n) {
  int t = blockIdx.x * blockDim.x + threadIdx.x;
  if (t >= n) return;
  int s = (int)(keys[t] & 0x3FFFFULL);
  ind2[t] = s;
  g2[t] = inv1[s];
}

// ======================= weight folding (f16, transposed) =======================
// A1 = (Wq Wk^T)^T * inv_scale, A2 = (Wv Wo)^T, A3 = Wout^T
__global__ void prep_all(const float* __restrict__ Wq1, const float* __restrict__ Wk1,
                         const float* __restrict__ Wv1, const float* __restrict__ Wo1,
                         const float* __restrict__ Wout1,
                         const float* __restrict__ Wq2, const float* __restrict__ Wk2,
                         const float* __restrict__ Wv2, const float* __restrict__ Wo2,
                         const float* __restrict__ Wout2,
                         f16* __restrict__ A1a, f16* __restrict__ A2a, f16* __restrict__ A3a,
                         f16* __restrict__ A1b, f16* __restrict__ A2b, f16* __restrict__ A3b) {
  const int idx = blockIdx.x * blockDim.x + threadIdx.x;   // 16384 threads
  if (idx < 4096) {
    const int a = idx >> 6, b = idx & 63;
    float s1 = 0.f, s2 = 0.f;
    for (int c = 0; c < 64; c++) {
      s1 = fmaf(Wq1[b * 64 + c], Wk1[a * 64 + c], s1);
      s2 = fmaf(Wv1[b * 64 + c], Wo1[c * 64 + a], s2);
    }
    A1a[idx] = (f16)(s1 * 0.125f);
    A2a[idx] = (f16)s2;
  }
  if (idx < 8192) {
    const int o = idx >> 6, c = idx & 63;
    A3a[idx] = (f16)Wout1[c * 128 + o];
  }
  {
    const int a = idx >> 7, b = idx & 127;
    float s1 = 0.f, s2 = 0.f;
    for (int c = 0; c < 128; c++) {
      s1 = fmaf(Wq2[b * 128 + c], Wk2[a * 128 + c], s1);
      s2 = fmaf(Wv2[b * 128 + c], Wo2[c * 128 + a], s2);
    }
    A1b[idx] = (f16)(s1 * 0.08838834764831845f);
    A2b[idx] = (f16)s2;
    A3b[idx] = (f16)Wout2[b * 128 + a];    // A3b[o][c] = Wout2[c][o], o=a? (idx=o*128+c -> o=idx>>7=a, c=b)
  }
}

// ======================= MFMA attention block =======================
// All GEMMs computed as Y^T = W^T @ X^T:
//   A operand: pre-transposed weight (global f16) or LDS;  B: prev stage row-major LDS.
//   D frag (4 consecutive out-rows per lane) stores contiguously into next row-major tile.
// LDS row-major f16 tiles swizzled: byteAddr ^= (row&7)<<4  (conflict-free b128/b64).

template<int M, int K, int AMODE>   // AMODE: 0=global A[M][K]; 1=LDS rm rows(=c)[K]; 2=LDS h^T scalar (row-len M)
__device__ __forceinline__ void gemmT(const f16* __restrict__ Ag, const f16* __restrict__ lA,
                                      const f16* __restrict__ lB, int w, int lane,
                                      f32x4 (&acc)[M / 64][4]) {
  constexpr int CT = M / 64;
  const int lr = lane & 15, lk = lane >> 4;
  #pragma unroll
  for (int ks = 0; ks < K / 32; ks++) {
    const int k0 = ks * 32 + lk * 8;
    f16x8 Af[CT];
    #pragma unroll
    for (int ct = 0; ct < CT; ct++) {
      const int c = lr + (w * CT + ct) * 16;
      if (AMODE == 0) {
        Af[ct] = *(const f16x8*)(Ag + (size_t)c * K + k0);
      } else if (AMODE == 1) {
        Af[ct] = *(const f16x8*)((const char*)lA + (((c * K + k0) * 2) ^ ((c & 7) << 4)));
      } else {
        f16x8 a;
        #pragma unroll
        for (int e = 0; e < 8; e++) {
          const int j = k0 + e;
          a[e] = *(const f16*)((const char*)lA + (((j * M + c) * 2) ^ ((j & 7) << 4)));
        }
        Af[ct] = a;
      }
    }
    f16x8 Bf[4];
    #pragma unroll
    for (int qt = 0; qt < 4; qt++) {
      const int q = lr + qt * 16;
      Bf[qt] = *(const f16x8*)((const char*)lB + (((q * K + k0) * 2) ^ ((q & 7) << 4)));
    }
    #pragma unroll
    for (int ct = 0; ct < CT; ct++)
      #pragma unroll
      for (int qt = 0; qt < 4; qt++)
        acc[ct][qt] = __builtin_amdgcn_mfma_f32_16x16x32_f16(Af[ct], Bf[qt], acc[ct][qt], 0, 0, 0);
  }
}

template<int M, bool RELU>
__device__ __forceinline__ void storeT16(f16* __restrict__ dst, int w, int lane,
                                         const f32x4 (&acc)[M / 64][4]) {
  constexpr int CT = M / 64;
  #pragma unroll
  for (int ct = 0; ct < CT; ct++)
    #pragma unroll
    for (int qt = 0; qt < 4; qt++) {
      const int q = (lane & 15) + qt * 16;
      const int c0 = (w * CT + ct) * 16 + (lane >> 4) * 4;
      f16x4 v;
      #pragma unroll
      for (int r = 0; r < 4; r++) {
        float x = acc[ct][qt][r];
        if (RELU) x = fmaxf(x, 0.f);
        v[r] = (f16)x;
      }
      *(f16x4*)((char*)dst + (((q * M + c0) * 2) ^ ((q & 7) << 4))) = v;
    }
}

template<int C, bool X16, bool OUT16>
__global__ __launch_bounds__(256, 3) void block_mfma(
    const int* __restrict__ idx_p, const int* __restrict__ idx_x,
    const float* __restrict__ pts, const void* __restrict__ xsrc,
    const float* __restrict__ Wpos, const float* __restrict__ bpos,
    const f16* __restrict__ A1, const f16* __restrict__ A2, const f16* __restrict__ A3,
    void* __restrict__ outp) {
  extern __shared__ char smem[];
  f16*   bufH = (f16*)smem;                    // [64][C] h  -> later o2r
  f16*   bufT = bufH + 64 * C;                 // [64][C] t1 -> later t2
  float* scF  = (float*)(bufT + 64 * C);       // [64][64] f32 scores -> later attn f16

  const int g = blockIdx.x;
  const int t = threadIdx.x;
  const int lane = t & 63;
  const int w = t >> 6;

  // ---- h = x * ((p-mean)@Wpos + bpos) -> bufH (f16 rm, swizzled) ----
  {
    const int qr = t & 63;
    const int spr = idx_p[g * 64 + qr];
    float mx = pts[spr * 3 + 0], my = pts[spr * 3 + 1], mz = pts[spr * 3 + 2];
    #pragma unroll
    for (int o = 32; o > 0; o >>= 1) {
      mx += __shfl_xor(mx, o); my += __shfl_xor(my, o); mz += __shfl_xor(mz, o);
    }
    mx *= (1.f / 64.f); my *= (1.f / 64.f); mz *= (1.f / 64.f);

    const int q = t >> 2, qq = t & 3;
    const int sp = idx_p[g * 64 + q];
    const float d0 = pts[sp * 3 + 0] - mx;
    const float d1 = pts[sp * 3 + 1] - my;
    const float d2 = pts[sp * 3 + 2] - mz;
    const int sx = idx_x[g * 64 + q];
    #pragma unroll
    for (int i = 0; i < C / 32; i++) {
      const int c0 = qq * (C / 4) + i * 8;
      float xv[8];
      if (X16) {
        f16x8 xr = *(const f16x8*)((const f16*)xsrc + (size_t)sx * C + c0);
        #pragma unroll
        for (int j = 0; j < 8; j++) xv[j] = (float)xr[j];
      } else {
        float4 x0 = *(const float4*)((const float*)xsrc + (size_t)sx * C + c0);
        float4 x1 = *(const float4*)((const float*)xsrc + (size_t)sx * C + c0 + 4);
        xv[0] = x0.x; xv[1] = x0.y; xv[2] = x0.z; xv[3] = x0.w;
        xv[4] = x1.x; xv[5] = x1.y; xv[6] = x1.z; xv[7] = x1.w;
      }
      f16x8 hv;
      #pragma unroll
      for (int jj = 0; jj < 8; jj += 4) {
        const float4 w0 = *(const float4*)(Wpos + 0 * C + c0 + jj);
        const float4 w1 = *(const float4*)(Wpos + 1 * C + c0 + jj);
        const float4 w2 = *(const float4*)(Wpos + 2 * C + c0 + jj);
        const float4 bb = *(const float4*)(bpos + c0 + jj);
        hv[jj + 0] = (f16)(xv[jj + 0] * fmaf(d0, w0.x, fmaf(d1, w1.x, fmaf(d2, w2.x, bb.x))));
        hv[jj + 1] = (f16)(xv[jj + 1] * fmaf(d0, w0.y, fmaf(d1, w1.y, fmaf(d2, w2.y, bb.y))));
        hv[jj + 2] = (f16)(xv[jj + 2] * fmaf(d0, w0.z, fmaf(d1, w1.z, fmaf(d2, w2.z, bb.z))));
        hv[jj + 3] = (f16)(xv[jj + 3] * fmaf(d0, w0.w, fmaf(d1, w1.w, fmaf(d2, w2.w, bb.w))));
      }
      *(f16x8*)((char*)bufH + (((q * C + c0) * 2) ^ ((q & 7) << 4))) = hv;
    }
  }
  __syncthreads();

  // ---- m1: t1^T = A1 @ h^T  -> bufT ----
  {
    f32x4 acc[C / 64][4] = {};
    gemmT<C, C, 0>(A1, nullptr, bufH, w, lane, acc);
    storeT16<C, false>(bufT, w, lane, acc);
  }
  __syncthreads();

  // ---- m3: sc^T[j][q] = h @ t1^T (A=h LDS, B=t1) -> scF f32 [q][j] ----
  {
    f32x4 acc[1][4] = {};
    gemmT<64, C, 1>(nullptr, bufH, bufT, w, lane, acc);
    #pragma unroll
    for (int qt = 0; qt < 4; qt++) {
      const int q = (lane & 15) + qt * 16;
      const int j0 = w * 16 + (lane >> 4) * 4;
      *(f32x4*)((char*)scF + (((q * 64 + j0) * 4) ^ ((q & 7) << 4))) = acc[0][qt];
    }
  }
  __syncthreads();

  // ---- softmax rows of sc -> attn f16 (same region) ----
  {
    const int q = t >> 2, qq = t & 3;
    float v[16];
    float mxv = -3.0e38f;
    #pragma unroll
    for (int i = 0; i < 4; i++) {
      f32x4 x = *(const f32x4*)((const char*)scF + (((q * 64 + qq * 16 + i * 4) * 4) ^ ((q & 7) << 4)));
      v[i * 4 + 0] = x[0]; v[i * 4 + 1] = x[1]; v[i * 4 + 2] = x[2]; v[i * 4 + 3] = x[3];
      mxv = fmaxf(mxv, fmaxf(fmaxf(x[0], x[1]), fmaxf(x[2], x[3])));
    }
    mxv = fmaxf(mxv, __shfl_xor(mxv, 1));
    mxv = fmaxf(mxv, __shfl_xor(mxv, 2));
    float s = 0.f;
    #pragma unroll
    for (int i = 0; i < 16; i++) { v[i] = __expf(v[i] - mxv); s += v[i]; }
    s += __shfl_xor(s, 1);
    s += __shfl_xor(s, 2);
    const float inv = 1.f / s;
    __syncthreads();
    f16* at = (f16*)scF;
    #pragma unroll
    for (int hhalf = 0; hhalf < 2; hhalf++) {
      f16x8 pk;
      #pragma unroll
      for (int j = 0; j < 8; j++) pk[j] = (f16)(v[hhalf * 8 + j] * inv);
      *(f16x8*)((char*)at + (((q * 64 + qq * 16 + hhalf * 8) * 2) ^ ((q & 7) << 4))) = pk;
    }
  }
  __syncthreads();

  // ---- m4: t2^T = h^T @ attn^T (A=h^T scalar from bufH, B=attn) -> bufT ----
  {
    f32x4 acc[C / 64][4] = {};
    gemmT<C, 64, 2>(nullptr, bufH, (const f16*)scF, w, lane, acc);
    storeT16<C, false>(bufT, w, lane, acc);
  }
  __syncthreads();

  // ---- m5: o2r^T = relu(A2 @ t2^T) -> bufH ----
  {
    f32x4 acc[C / 64][4] = {};
    gemmT<C, C, 0>(A2, nullptr, bufT, w, lane, acc);
    storeT16<C, true>(bufH, w, lane, acc);
  }
  __syncthreads();

  // ---- m6: y^T = A3 @ o2r^T -> global (M=128 always) ----
  {
    f32x4 acc[2][4] = {};
    gemmT<128, C, 0>(A3, nullptr, bufH, w, lane, acc);
    #pragma unroll
    for (int ct = 0; ct < 2; ct++)
      #pragma unroll
      for (int qt = 0; qt < 4; qt++) {
        const int q = (lane & 15) + qt * 16;
        const int o0 = (w * 2 + ct) * 16 + (lane >> 4) * 4;
        const size_t row = (size_t)g * 64 + q;
        if (OUT16) {
          f16x4 v;
          #pragma unroll
          for (int r = 0; r < 4; r++) v[r] = (f16)acc[ct][qt][r];
          *(f16x4*)((f16*)outp + row * 128 + o0) = v;
        } else {
          *(f32x4*)((float*)outp + row * 128 + o0) = acc[ct][qt];
        }
      }
  }
}

// ======================= finalize =======================
__global__ void finalize_k(const int* __restrict__ ind2, const float* __restrict__ pts,
                           const int* __restrict__ vox, const int* __restrict__ numbs,
                           float* __restrict__ out_pts, float* __restrict__ out_vox,
                           float* __restrict__ out_nb, int n, int B) {
  int t = blockIdx.x * blockDim.x + threadIdx.x;
  if (t < n) {
    const int s = ind2[t];
    out_pts[t * 3 + 0] = pts[s * 3 + 0];
    out_pts[t * 3 + 1] = pts[s * 3 + 1];
    out_pts[t * 3 + 2] = pts[s * 3 + 2];
    const int4 v = ((const int4*)vox)[s];
    out_vox[t * 4 + 0] = (float)v.x;
    out_vox[t * 4 + 1] = (float)v.y;
    out_vox[t * 4 + 2] = (float)v.z;
    out_vox[t * 4 + 3] = (float)v.w;
  }
  if (t < B) out_nb[t] = (float)numbs[t];
}

// ======================= host =======================
extern "C" void kernel_launch(void* const* d_in, const int* in_sizes, int n_in,
                              void* d_out, int out_size, void* d_ws, size_t ws_size,
                              hipStream_t stream) {
  const int*   vox_numbs = (const int*)d_in[0];
  const int*   vox_coors = (const int*)d_in[1];
  const float* vox_feats = (const float*)d_in[2];
  const float* pts_coors = (const float*)d_in[3];
  const float* Wpos1 = (const float*)d_in[4];
  const float* bpos1 = (const float*)d_in[5];
  const float* Wq1   = (const float*)d_in[6];
  const float* Wk1   = (const float*)d_in[7];
  const float* Wv1   = (const float*)d_in[8];
  const float* Wo1   = (const float*)d_in[9];
  const float* Wout1 = (const float*)d_in[10];
  const float* Wpos2 = (const float*)d_in[11];
  const float* bpos2 = (const float*)d_in[12];
  const float* Wq2   = (const float*)d_in[13];
  const float* Wk2   = (const float*)d_in[14];
  const float* Wv2   = (const float*)d_in[15];
  const float* Wo2   = (const float*)d_in[16];
  const float* Wout2 = (const float*)d_in[17];

  const int B = in_sizes[0];
  const int n = in_sizes[1] / 4;       // 262144 = 2^18
  const int ngrp = n / 64;

  char* w = (char*)d_ws;
  auto alloc = [&](size_t bytes) {
    char* p = w;
    w += (bytes + 255) & ~(size_t)255;
    return p;
  };
  u64* keys    = (u64*)alloc((size_t)2 * n * 8);   // keys1 | keys2 contiguous
  int* ind1    = (int*)alloc((size_t)n * 4);
  int* ind2    = (int*)alloc((size_t)n * 4);
  int* inv1    = (int*)alloc((size_t)n * 4);
  int* g2      = (int*)alloc((size_t)n * 4);
  f16* A1a     = (f16*)alloc(64 * 64 * 2);
  f16* A2a     = (f16*)alloc(64 * 64 * 2);
  f16* A3a     = (f16*)alloc(128 * 64 * 2);
  f16* A1b     = (f16*)alloc(128 * 128 * 2);
  f16* A2b     = (f16*)alloc(128 * 128 * 2);
  f16* A3b     = (f16*)alloc(128 * 128 * 2);
  f16* feats1  = (f16*)alloc((size_t)n * 128 * 2);
  u64* keys2   = keys + n;

  float* out_feats = (float*)d_out;
  float* out_pts   = out_feats + (size_t)n * 128;
  float* out_vox   = out_pts + (size_t)n * 3;
  float* out_nb    = out_vox + (size_t)n * 4;

  auto f64k  = block_mfma<64,  false, true>;
  auto f128k = block_mfma<128, true,  false>;
  hipFuncSetAttribute((const void*)f64k,  hipFuncAttributeMaxDynamicSharedMemorySize, 65536);
  hipFuncSetAttribute((const void*)f128k, hipFuncAttributeMaxDynamicSharedMemorySize, 65536);

  encode_keys<<<(n + 255) / 256, 256, 0, stream>>>(vox_coors, keys, keys2, n);
  prep_all<<<64, 256, 0, stream>>>(Wq1, Wk1, Wv1, Wo1, Wout1, Wq2, Wk2, Wv2, Wo2, Wout2,
                                   A1a, A2a, A3a, A1b, A2b, A3b);

  // ---- fused bitonic sort over both key arrays ----
  {
    const dim3 gt(n / 2048, 2);
    const dim3 g1(n / 512, 2), g2d(n / 1024, 2), g3d(n / 2048, 2);
    bitonic_tile_sort<<<gt, 1024, 0, stream>>>(keys, n);
    for (int k = 4096; k <= n; k <<= 1) {
      int levels = 0;
      for (int j = k >> 1; j >= 2048; j >>= 1) levels++;
      int j = k >> 1;
      while (levels >= 3) {
        bitonic_g3<<<g3d, 256, 0, stream>>>(keys, j >> 2, k, n);
        j >>= 3; levels -= 3;
      }
      if (levels == 2) { bitonic_g2<<<g2d, 256, 0, stream>>>(keys, j >> 1, k, n); j >>= 2; levels = 0; }
      else if (levels == 1) { bitonic_g1<<<g1, 256, 0, stream>>>(keys, j, k, n); j >>= 1; levels = 0; }
      bitonic_tile_merge<<<gt, 1024, 0, stream>>>(keys, k, n);
    }
  }
  extract_inv_k<<<(n + 255) / 256, 256, 0, stream>>>(keys, ind1, inv1, n);
  make_g2_k<<<(n + 255) / 256, 256, 0, stream>>>(keys2, inv1, ind2, g2, n);

  block_mfma<64, false, true><<<ngrp, 256, 32768, stream>>>(
      ind1, ind1, pts_coors, vox_feats, Wpos1, bpos1, A1a, A2a, A3a, feats1);
  block_mfma<128, true, false><<<ngrp, 256, 49152, stream>>>(
      ind2, g2, pts_coors, feats1, Wpos2, bpos2, A1b, A2b, A3b, out_feats);

  finalize_k<<<(n + 255) / 256, 256, 0, stream>>>(ind2, pts_coors, vox_coors, vox_numbs,
                                                  out_pts, out_vox, out_nb, n, B);
}